// Round 3
// baseline (2032.614 us; speedup 1.0000x reference)
//
#include <hip/hip_runtime.h>
#include <hip/hip_bf16.h>
#include <cstdint>

// Problem constants
#define NB     16384   // batch
#define DIN    1024
#define HID    2048
#define NE     8
#define NC     8
#define DZ     256

// Main GEMM tiling
#define BM     128     // hidden rows per chunk
#define BNB    128     // batch cols per tile
#define NCHUNK (HID/BM)    // 16
#define KSTEPS 32          // 32 k-steps of 32 elems = DIN

typedef short bf16x8 __attribute__((ext_vector_type(8)));
typedef float f32x4  __attribute__((ext_vector_type(4)));

__device__ __forceinline__ unsigned short f2bf(float f) {
    unsigned int u = __float_as_uint(f);
    unsigned int r = (u + 0x7FFFu + ((u >> 16) & 1u)) >> 16;
    return (unsigned short)r;
}

// ---------------------------------------------------------------------------
// Gate: w = softmax(cos_sim(z, mu)/tau). One wave per row. Also zeroes logits.
// ---------------------------------------------------------------------------
__global__ __launch_bounds__(256) void k_gate(const float* __restrict__ z,
                                              const float* __restrict__ mu,
                                              const int* __restrict__ tau_i,
                                              float* __restrict__ wout,
                                              float* __restrict__ logits) {
    int row = blockIdx.x * 4 + (threadIdx.x >> 6);
    int l = threadIdx.x & 63;
    float4 zv = *(const float4*)&z[(size_t)row * DZ + l * 4];
    float zz = zv.x * zv.x + zv.y * zv.y + zv.z * zv.z + zv.w * zv.w;
    float dots[NE], mm[NE];
#pragma unroll
    for (int e = 0; e < NE; ++e) {
        float4 m = *(const float4*)&mu[e * DZ + l * 4];
        dots[e] = zv.x * m.x + zv.y * m.y + zv.z * m.z + zv.w * m.w;
        mm[e]   = m.x * m.x + m.y * m.y + m.z * m.z + m.w * m.w;
    }
#pragma unroll
    for (int off = 32; off; off >>= 1) {
        zz += __shfl_xor(zz, off);
#pragma unroll
        for (int e = 0; e < NE; ++e) {
            dots[e] += __shfl_xor(dots[e], off);
            mm[e]   += __shfl_xor(mm[e], off);
        }
    }
    float zn = fmaxf(sqrtf(zz), 1e-12f);
    float tau = fmaxf(1e-6f, (float)tau_i[0]);
    float s[NE], mx = -1e30f;
#pragma unroll
    for (int e = 0; e < NE; ++e) {
        s[e] = dots[e] / (zn * fmaxf(sqrtf(mm[e]), 1e-12f)) / tau;
        mx = fmaxf(mx, s[e]);
    }
    float sum = 0.f;
#pragma unroll
    for (int e = 0; e < NE; ++e) { s[e] = expf(s[e] - mx); sum += s[e]; }
    float inv = 1.f / sum;
    if (l < NE) {
        wout[(size_t)row * NE + l]   = s[l] * inv;
        logits[(size_t)row * NE + l] = 0.f;   // zero-init for atomics
    }
}

// ---------------------------------------------------------------------------
// LayerNorm (shared part) -> bf16 xhat. One block per row.
// ---------------------------------------------------------------------------
__global__ __launch_bounds__(256) void k_ln(const float* __restrict__ feat,
                                            unsigned short* __restrict__ xhat) {
    int row = blockIdx.x;
    int t = threadIdx.x;
    float4 v = *(const float4*)&feat[(size_t)row * DIN + t * 4];
    float s  = v.x + v.y + v.z + v.w;
    float sq = v.x * v.x + v.y * v.y + v.z * v.z + v.w * v.w;
#pragma unroll
    for (int off = 32; off; off >>= 1) {
        s  += __shfl_down(s, off);
        sq += __shfl_down(sq, off);
    }
    __shared__ float ls[8];
    int w = t >> 6, l = t & 63;
    if (l == 0) { ls[w] = s; ls[4 + w] = sq; }
    __syncthreads();
    s  = ls[0] + ls[1] + ls[2] + ls[3];
    sq = ls[4] + ls[5] + ls[6] + ls[7];
    float mean = s * (1.f / DIN);
    float var  = sq * (1.f / DIN) - mean * mean;
    float r = 1.0f / sqrtf(var + 1e-5f);
    uint2 p;
    p.x = (unsigned)f2bf((v.x - mean) * r) | ((unsigned)f2bf((v.y - mean) * r) << 16);
    p.y = (unsigned)f2bf((v.z - mean) * r) | ((unsigned)f2bf((v.w - mean) * r) << 16);
    *(uint2*)&xhat[(size_t)row * DIN + t * 4] = p;
}

// ---------------------------------------------------------------------------
// W2 transpose->bf16 (padded [E][16][HID]) and b1p init (copy of b1).
// ---------------------------------------------------------------------------
__global__ __launch_bounds__(256) void k_w2prep(const float* __restrict__ W2,
                                                const float* __restrict__ b1,
                                                unsigned short* __restrict__ w2t,
                                                float* __restrict__ b1p) {
    int i = blockIdx.x * 256 + threadIdx.x;   // 8*16*2048 = 262144
    int e = i >> 15;
    int rem = i & 32767;
    int c = rem >> 11;
    int h = rem & 2047;
    float v = (c < NC) ? W2[((size_t)(e * HID + h)) * NC + c] : 0.f;
    w2t[i] = f2bf(v);
    if (i < NE * HID) b1p[i] = b1[i];
}

// ---------------------------------------------------------------------------
// W1 fold+transpose: W1t[e][h][d] = bf16(gamma[e][d] * W1[e][d][h]);
// b1p[e][h] += sum_d beta[e][d]*W1[e][d][h].  64x64 LDS tile transpose.
// ---------------------------------------------------------------------------
__global__ __launch_bounds__(256) void k_w1prep(const float* __restrict__ W1,
                                                const float* __restrict__ gamma,
                                                const float* __restrict__ beta,
                                                unsigned short* __restrict__ w1t,
                                                float* __restrict__ b1p) {
    __shared__ float tile[64][65];   // [h-local][d-local], unscaled
    int e  = blockIdx.z;
    int d0 = blockIdx.y * 64;
    int h0 = blockIdx.x * 64;
    int tx = threadIdx.x & 15, ty = threadIdx.x >> 4;
#pragma unroll
    for (int rr = 0; rr < 4; ++rr) {
        int d = ty + rr * 16;
        float4 v = *(const float4*)&W1[((size_t)e * DIN + d0 + d) * HID + h0 + tx * 4];
        tile[tx * 4 + 0][d] = v.x;
        tile[tx * 4 + 1][d] = v.y;
        tile[tx * 4 + 2][d] = v.z;
        tile[tx * 4 + 3][d] = v.w;
    }
    __syncthreads();
    float4 g = *(const float4*)&gamma[(size_t)e * DIN + d0 + tx * 4];
#pragma unroll
    for (int rr = 0; rr < 4; ++rr) {
        int h = ty + rr * 16;
        uint2 p;
        p.x = (unsigned)f2bf(tile[h][tx * 4 + 0] * g.x) |
              ((unsigned)f2bf(tile[h][tx * 4 + 1] * g.y) << 16);
        p.y = (unsigned)f2bf(tile[h][tx * 4 + 2] * g.z) |
              ((unsigned)f2bf(tile[h][tx * 4 + 3] * g.w) << 16);
        *(uint2*)&w1t[((size_t)e * HID + h0 + h) * DIN + d0 + tx * 4] = p;
    }
    if (threadIdx.x < 64) {
        int h = threadIdx.x;
        float sacc = 0.f;
        for (int r = 0; r < 64; ++r)
            sacc += beta[(size_t)e * DIN + d0 + r] * tile[h][r];
        atomicAdd(&b1p[(size_t)e * HID + h0 + h], sacc);
    }
}

// ---------------------------------------------------------------------------
// Fused main kernel, R2: BARRIER-FREE K-loop. Both MFMA operands are loaded
// directly from global into VGPR fragments (per lane (q,ml): 16 contiguous
// bytes at row ..+ml, k=8q; the 4 q-lanes of one ml form one 64B line), with
// a 1-round software-pipelined rotation (a0/b0 <-> a1/b1). No LDS staging,
// no __syncthreads in the K-loop: R1's counters showed ~984 cyc/round vs
// ~310 cyc of compute -- the vmcnt(0)+barrier drain at 2 blocks/CU
// (register-quantum capped: 72 VGPR + 80 AGPR -> 8 waves/CU) was the wall.
// Free-running waves + in-wave pipelining hide the latency instead.
// ---------------------------------------------------------------------------
__global__ __launch_bounds__(256, 2) void moe_main(
        const unsigned short* __restrict__ xhat,   // [B][DIN] bf16
        const unsigned short* __restrict__ w1t,    // [E][HID][DIN] bf16
        const float* __restrict__ b1p,             // [E][HID]
        const unsigned short* __restrict__ w2t,    // [E][16][HID] bf16 (c>=8 zero)
        const float* __restrict__ b2,              // [E][NC]
        const float* __restrict__ wg,              // [B][NE]
        float* __restrict__ logits) {              // [B][NC]
    __shared__ __align__(16) char lds_ht[4 * 64 * 144];  // 36 KB per-wave hT

    const int t = threadIdx.x;
    const int w = t >> 6, l = t & 63;
    const int q = l >> 4, ml = l & 15;
    const int flat = blockIdx.x;
    const int e = flat & 7;           // e-inner for L2 sharing of xhat tiles
    const int btile = flat >> 3;
    const int b0 = btile * BNB;
    const int wm = (w >> 1) * 64;     // wave's hid-half
    const int wn = (w & 1) * 64;      // wave's b-half

    // Per-lane fragment base pointers (row = ..+ml, k-offset = 8*q elems)
    const unsigned short* pa =
        w1t + (size_t)e * HID * DIN + (size_t)(wm + ml) * DIN + 8 * q;
    const unsigned short* pb =
        xhat + (size_t)(b0 + wn + ml) * DIN + 8 * q;
    char* myht = lds_ht + w * 9216;   // 64 rows(b) x 144 B

#define LOADA(dst, ch_, k0_)                                                  \
    {                                                                         \
        _Pragma("unroll")                                                     \
        for (int i_ = 0; i_ < 4; ++i_)                                        \
            dst[i_] = *(const bf16x8*)(pa + ((size_t)((ch_) * BM + 16 * i_)) * DIN + (k0_)); \
    }
#define LOADB(dst, k0_)                                                       \
    {                                                                         \
        _Pragma("unroll")                                                     \
        for (int j_ = 0; j_ < 4; ++j_)                                        \
            dst[j_] = *(const bf16x8*)(pb + (size_t)(16 * j_) * DIN + (k0_)); \
    }
#define MFMA16(af, bf)                                                        \
    {                                                                         \
        _Pragma("unroll")                                                     \
        for (int i_ = 0; i_ < 4; ++i_)                                        \
            _Pragma("unroll")                                                 \
            for (int j_ = 0; j_ < 4; ++j_)                                    \
                acc[i_][j_] = __builtin_amdgcn_mfma_f32_16x16x32_bf16(        \
                    af[i_], bf[j_], acc[i_][j_], 0, 0, 0);                    \
    }

    f32x4 acc2[4];
#pragma unroll
    for (int tb = 0; tb < 4; ++tb) acc2[tb] = (f32x4){0.f, 0.f, 0.f, 0.f};

    bf16x8 a0[4], b0f[4], a1[4], b1f[4];
    LOADA(a0, 0, 0);
    LOADB(b0f, 0);

    for (int ch = 0; ch < NCHUNK; ++ch) {
        f32x4 acc[4][4];
#pragma unroll
        for (int i = 0; i < 4; ++i)
#pragma unroll
            for (int j = 0; j < 4; ++j) acc[i][j] = (f32x4){0.f, 0.f, 0.f, 0.f};

        for (int ks = 0; ks < KSTEPS; ks += 2) {
            // prefetch round ks+1, compute round ks
            LOADA(a1, ch, (ks + 1) * 32);
            LOADB(b1f, (ks + 1) * 32);
            MFMA16(a0, b0f);
            // prefetch round ks+2 (wraps into next chunk / harmless re-read)
            int nks = (ks + 2) & (KSTEPS - 1);
            int nch = (nks == 0) ? ch + 1 : ch;
            if (nch == NCHUNK) nch = 0;   // last round: harmless dummy
            LOADA(a0, nch, nks * 32);
            LOADB(b0f, nks * 32);
            MFMA16(a1, b1f);
        }

        // ---- chunk epilogue: bias+relu -> bf16 -> per-wave LDS [b][hid] ----
        // (next chunk's first loads are already in flight above)
#pragma unroll
        for (int i = 0; i < 4; ++i) {
            const float4 bias =
                *(const float4*)&b1p[(size_t)e * HID + ch * BM + wm + 16 * i + 4 * q];
#pragma unroll
            for (int j = 0; j < 4; ++j) {
                float v0 = fmaxf(acc[i][j].x + bias.x, 0.f);
                float v1 = fmaxf(acc[i][j].y + bias.y, 0.f);
                float v2 = fmaxf(acc[i][j].z + bias.z, 0.f);
                float v3 = fmaxf(acc[i][j].w + bias.w, 0.f);
                uint2 p;
                p.x = (unsigned)f2bf(v0) | ((unsigned)f2bf(v1) << 16);
                p.y = (unsigned)f2bf(v2) | ((unsigned)f2bf(v3) << 16);
                const int brow = 16 * j + ml;   // local b in wave (0..63)
                *(uint2*)(myht + brow * 144 + (16 * i + 4 * q) * 2) = p;
            }
        }
        // ---- second GEMM: acc2 += hT_chunk @ W2 (wave-private, no barrier) ----
#pragma unroll
        for (int s = 0; s < 2; ++s) {
            const bf16x8 b2f = *(const bf16x8*)&w2t[((size_t)e * 16 + ml) * HID +
                                                    ch * BM + wm + 32 * s + 8 * q];
#pragma unroll
            for (int tb = 0; tb < 4; ++tb) {
                const bf16x8 a2f =
                    *(const bf16x8*)(myht + (16 * tb + ml) * 144 + (32 * s + 8 * q) * 2);
                acc2[tb] = __builtin_amdgcn_mfma_f32_16x16x32_bf16(
                    a2f, b2f, acc2[tb], 0, 0, 0);
            }
        }
    }

    // ---- cross-wave (hid-half) reduction of acc2, then gated atomic store ----
    __syncthreads();
    float* red = (float*)lds_ht;
    if (w >= 2) {
        float* dst = red + ((size_t)((w & 1) * 64 + l)) * 16;
#pragma unroll
        for (int tb = 0; tb < 4; ++tb)
#pragma unroll
            for (int r = 0; r < 4; ++r) dst[tb * 4 + r] = acc2[tb][r];
    }
    __syncthreads();
    if (w < 2) {
        const float* src = red + ((size_t)((w & 1) * 64 + l)) * 16;
        const int c = ml;   // D2 col = lane&15
        if (c < NC) {
            const float b2v = b2[e * NC + c];
#pragma unroll
            for (int tb = 0; tb < 4; ++tb) {
#pragma unroll
                for (int r = 0; r < 4; ++r) {
                    float v = acc2[tb][r] + src[tb * 4 + r];
                    const int bg = b0 + wn + 16 * tb + 4 * q + r;
                    const float wgt = wg[(size_t)bg * NE + e];
                    atomicAdd(&logits[(size_t)bg * NC + c], wgt * (v + b2v));
                }
            }
        }
    }
}

// ---------------------------------------------------------------------------
extern "C" void kernel_launch(void* const* d_in, const int* in_sizes, int n_in,
                              void* d_out, int out_size, void* d_ws, size_t ws_size,
                              hipStream_t stream) {
    const float* feat  = (const float*)d_in[0];
    const float* z     = (const float*)d_in[1];
    const float* mu    = (const float*)d_in[2];
    const float* gamma = (const float*)d_in[3];
    const float* beta  = (const float*)d_in[4];
    const float* W1    = (const float*)d_in[5];
    const float* b1    = (const float*)d_in[6];
    const float* W2    = (const float*)d_in[7];
    const float* b2    = (const float*)d_in[8];
    const int*   tau   = (const int*)d_in[9];

    float* logits = (float*)d_out;                 // [B][NC]
    float* wout   = logits + (size_t)NB * NC;      // [B][NE]

    char* ws = (char*)d_ws;
    unsigned short* xhat = (unsigned short*)ws;                       // 33.5 MB
    unsigned short* w1t  = (unsigned short*)(ws + 33554432);          // 33.5 MB
    unsigned short* w2t  = (unsigned short*)(ws + 67108864);          // 0.5 MB
    float*          b1p  = (float*)(ws + 67633152);                   // 64 KB

    k_gate<<<NB / 4, 256, 0, stream>>>(z, mu, tau, wout, logits);
    k_ln<<<NB, 256, 0, stream>>>(feat, xhat);
    k_w2prep<<<(NE * 16 * HID) / 256, 256, 0, stream>>>(W2, b1, w2t, b1p);
    k_w1prep<<<dim3(HID / 64, DIN / 64, NE), 256, 0, stream>>>(W1, gamma, beta, w1t, b1p);
    moe_main<<<dim3((NB / BNB) * NE), 256, 0, stream>>>(xhat, w1t, b1p, w2t, b2,
                                                        wout, logits);
}

// Round 4
// 896.782 us; speedup vs baseline: 2.2666x; 2.2666x over previous
//
#include <hip/hip_runtime.h>
#include <hip/hip_bf16.h>
#include <cstdint>

// Problem constants
#define NB     16384   // batch
#define DIN    1024
#define HID    2048
#define NE     8
#define NC     8
#define DZ     256

// Main GEMM tiling
#define BM     128     // hidden rows per chunk
#define BNB    128     // batch cols per tile
#define BK     32
#define KSTEPS (DIN/BK)    // 32
#define NUNITS 2048        // 128 btiles x 8 experts x 2 hid-halves
#define GRID_MAIN 768      // 3 blocks/CU persistent

typedef short bf16x8 __attribute__((ext_vector_type(8)));
typedef float f32x4  __attribute__((ext_vector_type(4)));

__device__ __forceinline__ unsigned short f2bf(float f) {
    unsigned int u = __float_as_uint(f);
    unsigned int r = (u + 0x7FFFu + ((u >> 16) & 1u)) >> 16;
    return (unsigned short)r;
}

__device__ __forceinline__ void async_copy16(const void* g, void* l) {
    __builtin_amdgcn_global_load_lds(
        (const __attribute__((address_space(1))) unsigned int*)g,
        (__attribute__((address_space(3))) unsigned int*)l, 16, 0, 0);
}

// ---------------------------------------------------------------------------
// Gate: w = softmax(cos_sim(z, mu)/tau). One wave per row. Also zeroes logits.
// ---------------------------------------------------------------------------
__global__ __launch_bounds__(256) void k_gate(const float* __restrict__ z,
                                              const float* __restrict__ mu,
                                              const int* __restrict__ tau_i,
                                              float* __restrict__ wout,
                                              float* __restrict__ logits) {
    int row = blockIdx.x * 4 + (threadIdx.x >> 6);
    int l = threadIdx.x & 63;
    float4 zv = *(const float4*)&z[(size_t)row * DZ + l * 4];
    float zz = zv.x * zv.x + zv.y * zv.y + zv.z * zv.z + zv.w * zv.w;
    float dots[NE], mm[NE];
#pragma unroll
    for (int e = 0; e < NE; ++e) {
        float4 m = *(const float4*)&mu[e * DZ + l * 4];
        dots[e] = zv.x * m.x + zv.y * m.y + zv.z * m.z + zv.w * m.w;
        mm[e]   = m.x * m.x + m.y * m.y + m.z * m.z + m.w * m.w;
    }
#pragma unroll
    for (int off = 32; off; off >>= 1) {
        zz += __shfl_xor(zz, off);
#pragma unroll
        for (int e = 0; e < NE; ++e) {
            dots[e] += __shfl_xor(dots[e], off);
            mm[e]   += __shfl_xor(mm[e], off);
        }
    }
    float zn = fmaxf(sqrtf(zz), 1e-12f);
    float tau = fmaxf(1e-6f, (float)tau_i[0]);
    float s[NE], mx = -1e30f;
#pragma unroll
    for (int e = 0; e < NE; ++e) {
        s[e] = dots[e] / (zn * fmaxf(sqrtf(mm[e]), 1e-12f)) / tau;
        mx = fmaxf(mx, s[e]);
    }
    float sum = 0.f;
#pragma unroll
    for (int e = 0; e < NE; ++e) { s[e] = expf(s[e] - mx); sum += s[e]; }
    float inv = 1.f / sum;
    if (l < NE) {
        wout[(size_t)row * NE + l]   = s[l] * inv;
        logits[(size_t)row * NE + l] = 0.f;   // zero-init for atomics
    }
}

// ---------------------------------------------------------------------------
// LayerNorm (shared part) -> bf16 xhat. One block per row.
// ---------------------------------------------------------------------------
__global__ __launch_bounds__(256) void k_ln(const float* __restrict__ feat,
                                            unsigned short* __restrict__ xhat) {
    int row = blockIdx.x;
    int t = threadIdx.x;
    float4 v = *(const float4*)&feat[(size_t)row * DIN + t * 4];
    float s  = v.x + v.y + v.z + v.w;
    float sq = v.x * v.x + v.y * v.y + v.z * v.z + v.w * v.w;
#pragma unroll
    for (int off = 32; off; off >>= 1) {
        s  += __shfl_down(s, off);
        sq += __shfl_down(sq, off);
    }
    __shared__ float ls[8];
    int w = t >> 6, l = t & 63;
    if (l == 0) { ls[w] = s; ls[4 + w] = sq; }
    __syncthreads();
    s  = ls[0] + ls[1] + ls[2] + ls[3];
    sq = ls[4] + ls[5] + ls[6] + ls[7];
    float mean = s * (1.f / DIN);
    float var  = sq * (1.f / DIN) - mean * mean;
    float r = 1.0f / sqrtf(var + 1e-5f);
    uint2 p;
    p.x = (unsigned)f2bf((v.x - mean) * r) | ((unsigned)f2bf((v.y - mean) * r) << 16);
    p.y = (unsigned)f2bf((v.z - mean) * r) | ((unsigned)f2bf((v.w - mean) * r) << 16);
    *(uint2*)&xhat[(size_t)row * DIN + t * 4] = p;
}

// ---------------------------------------------------------------------------
// W2 transpose->bf16 (padded [E][16][HID]), b1p init, and work-queue zero.
// ---------------------------------------------------------------------------
__global__ __launch_bounds__(256) void k_w2prep(const float* __restrict__ W2,
                                                const float* __restrict__ b1,
                                                unsigned short* __restrict__ w2t,
                                                float* __restrict__ b1p,
                                                int* __restrict__ qcounter) {
    int i = blockIdx.x * 256 + threadIdx.x;   // 8*16*2048 = 262144
    if (i == 0) qcounter[0] = 0;              // ws is re-poisoned each launch
    int e = i >> 15;
    int rem = i & 32767;
    int c = rem >> 11;
    int h = rem & 2047;
    float v = (c < NC) ? W2[((size_t)(e * HID + h)) * NC + c] : 0.f;
    w2t[i] = f2bf(v);
    if (i < NE * HID) b1p[i] = b1[i];
}

// ---------------------------------------------------------------------------
// W1 fold+transpose: W1t[e][h][d] = bf16(gamma[e][d] * W1[e][d][h]);
// b1p[e][h] += sum_d beta[e][d]*W1[e][d][h].  64x64 LDS tile transpose.
// ---------------------------------------------------------------------------
__global__ __launch_bounds__(256) void k_w1prep(const float* __restrict__ W1,
                                                const float* __restrict__ gamma,
                                                const float* __restrict__ beta,
                                                unsigned short* __restrict__ w1t,
                                                float* __restrict__ b1p) {
    __shared__ float tile[64][65];   // [h-local][d-local], unscaled
    int e  = blockIdx.z;
    int d0 = blockIdx.y * 64;
    int h0 = blockIdx.x * 64;
    int tx = threadIdx.x & 15, ty = threadIdx.x >> 4;
#pragma unroll
    for (int rr = 0; rr < 4; ++rr) {
        int d = ty + rr * 16;
        float4 v = *(const float4*)&W1[((size_t)e * DIN + d0 + d) * HID + h0 + tx * 4];
        tile[tx * 4 + 0][d] = v.x;
        tile[tx * 4 + 1][d] = v.y;
        tile[tx * 4 + 2][d] = v.z;
        tile[tx * 4 + 3][d] = v.w;
    }
    __syncthreads();
    float4 g = *(const float4*)&gamma[(size_t)e * DIN + d0 + tx * 4];
#pragma unroll
    for (int rr = 0; rr < 4; ++rr) {
        int h = ty + rr * 16;
        uint2 p;
        p.x = (unsigned)f2bf(tile[h][tx * 4 + 0] * g.x) |
              ((unsigned)f2bf(tile[h][tx * 4 + 1] * g.y) << 16);
        p.y = (unsigned)f2bf(tile[h][tx * 4 + 2] * g.z) |
              ((unsigned)f2bf(tile[h][tx * 4 + 3] * g.w) << 16);
        *(uint2*)&w1t[((size_t)e * HID + h0 + h) * DIN + d0 + tx * 4] = p;
    }
    if (threadIdx.x < 64) {
        int h = threadIdx.x;
        float sacc = 0.f;
        for (int r = 0; r < 64; ++r)
            sacc += beta[(size_t)e * DIN + d0 + r] * tile[h][r];
        atomicAdd(&b1p[(size_t)e * HID + h0 + h], sacc);
    }
}

// ---------------------------------------------------------------------------
// Fused main kernel, R3: persistent blocks (768 = 3/CU) + atomic work queue
// over 2048 half-units (btile, e, hid-half of 8 chunks). Unit order is
// btile-fastest so co-running blocks stream the SAME w1t region (L2 hits on
// the A-tile staging). LDS cut to 36.8 KB (epilogue split into two 32-hid
// passes, per-wave ht = 64 rows x 80 B) to fit 3 blocks/CU: R1's 52 KB
// capped residency at 2 and left a 4-over-2 phase structure with ~990 cyc
// barrier rounds vs ~310 cyc compute. K-loop itself is R1's verified
// swizzled global_load_lds structure.
// ---------------------------------------------------------------------------
__global__ __launch_bounds__(256, 3) void moe_main(
        const unsigned short* __restrict__ xhat,   // [B][DIN] bf16
        const unsigned short* __restrict__ w1t,    // [E][HID][DIN] bf16
        const float* __restrict__ b1p,             // [E][HID]
        const unsigned short* __restrict__ w2t,    // [E][16][HID] bf16 (c>=8 zero)
        const float* __restrict__ b2,              // [E][NC]
        const float* __restrict__ wg,              // [B][NE]
        float* __restrict__ logits,                // [B][NC]
        int* __restrict__ qcounter) {
    __shared__ __align__(16) short lds_a[BM * BK];      // 8 KB, swizzled
    __shared__ __align__(16) short lds_b[BNB * BK];     // 8 KB, swizzled
    __shared__ __align__(16) char  lds_ht[4 * 64 * 80]; // 20 KB per-wave hT
    __shared__ int s_u;

    const int t = threadIdx.x;
    const int w = t >> 6, l = t & 63;
    const int q = l >> 4, ml = l & 15;
    const int wm = (w >> 1) * 64;     // wave's hid-half within chunk
    const int wn = (w & 1) * 64;      // wave's b-half

    const int ldrow  = w * 16 + (l >> 2);                 // staging row in 64-half
    const int kslot8 = (((l & 3) ^ ((l >> 3) & 3))) * 8;  // swizzled k-chunk
    const int swz8   = (q ^ ((ml >> 1) & 3)) * 8;         // read-side swizzle
    char* myht = lds_ht + w * 5120;   // 64 rows(b) x 80 B

    for (;;) {
        if (t == 0) s_u = atomicAdd(qcounter, 1);
        __syncthreads();
        const int u = s_u;
        if (u >= NUNITS) break;
        const int btile = u & 127;
        const int e     = (u >> 7) & 7;
        const int half  = u >> 10;
        const int b0 = btile * BNB;
        const unsigned short* gA = w1t + (size_t)e * HID * DIN;
        const unsigned short* gB = xhat + (size_t)b0 * DIN;

        f32x4 acc2[4];
#pragma unroll
        for (int tb = 0; tb < 4; ++tb) acc2[tb] = (f32x4){0.f, 0.f, 0.f, 0.f};

        for (int ch = half * 8; ch < half * 8 + 8; ++ch) {
            const int hid0 = ch * BM;
            f32x4 acc[4][4];
#pragma unroll
            for (int i = 0; i < 4; ++i)
#pragma unroll
                for (int j = 0; j < 4; ++j) acc[i][j] = (f32x4){0.f, 0.f, 0.f, 0.f};

            for (int ks = 0; ks < KSTEPS; ++ks) {
                const int k0 = ks * BK;
#pragma unroll
                for (int it = 0; it < 2; ++it) {
                    const int row = it * 64 + ldrow;
                    async_copy16(gA + (size_t)(hid0 + row) * DIN + k0 + kslot8,
                                 (char*)lds_a + it * 4096 + w * 1024 + (l << 4));
                    async_copy16(gB + (size_t)row * DIN + k0 + kslot8,
                                 (char*)lds_b + it * 4096 + w * 1024 + (l << 4));
                }
                __syncthreads();   // drains vmcnt before barrier (m97 pattern)
                bf16x8 aF[4], bF[4];
#pragma unroll
                for (int i = 0; i < 4; ++i)
                    aF[i] = *(const bf16x8*)&lds_a[(wm + 16 * i + ml) * BK + swz8];
#pragma unroll
                for (int j = 0; j < 4; ++j)
                    bF[j] = *(const bf16x8*)&lds_b[(wn + 16 * j + ml) * BK + swz8];
#pragma unroll
                for (int i = 0; i < 4; ++i)
#pragma unroll
                    for (int j = 0; j < 4; ++j)
                        acc[i][j] = __builtin_amdgcn_mfma_f32_16x16x32_bf16(
                            aF[i], bF[j], acc[i][j], 0, 0, 0);
                __syncthreads();   // all waves done reading before next stage
            }

            // ---- chunk epilogue, 2 passes of 32 hid each ----
#pragma unroll
            for (int s = 0; s < 2; ++s) {
#pragma unroll
                for (int i2 = 0; i2 < 2; ++i2) {
                    const int i = 2 * s + i2;
                    const float4 bias = *(const float4*)
                        &b1p[(size_t)e * HID + hid0 + wm + 16 * i + 4 * q];
#pragma unroll
                    for (int j = 0; j < 4; ++j) {
                        float v0 = fmaxf(acc[i][j].x + bias.x, 0.f);
                        float v1 = fmaxf(acc[i][j].y + bias.y, 0.f);
                        float v2 = fmaxf(acc[i][j].z + bias.z, 0.f);
                        float v3 = fmaxf(acc[i][j].w + bias.w, 0.f);
                        uint2 p;
                        p.x = (unsigned)f2bf(v0) | ((unsigned)f2bf(v1) << 16);
                        p.y = (unsigned)f2bf(v2) | ((unsigned)f2bf(v3) << 16);
                        const int brow = 16 * j + ml;   // local b (0..63)
                        *(uint2*)(myht + brow * 80 + (16 * i2 + 4 * q) * 2) = p;
                    }
                }
                // second GEMM over this 32-hid slab (wave-private ht)
                const bf16x8 b2f = *(const bf16x8*)&w2t[((size_t)e * 16 + ml) * HID +
                                                        hid0 + wm + 32 * s + 8 * q];
#pragma unroll
                for (int tb = 0; tb < 4; ++tb) {
                    const bf16x8 a2f =
                        *(const bf16x8*)(myht + (16 * tb + ml) * 80 + q * 16);
                    acc2[tb] = __builtin_amdgcn_mfma_f32_16x16x32_bf16(
                        a2f, b2f, acc2[tb], 0, 0, 0);
                }
            }
        }

        // ---- cross-wave (hid-half) reduction of acc2, gated atomic store ----
        __syncthreads();
        float* red = (float*)lds_ht;
        if (w >= 2) {
            float* dst = red + ((size_t)((w & 1) * 64 + l)) * 16;
#pragma unroll
            for (int tb = 0; tb < 4; ++tb)
#pragma unroll
                for (int r = 0; r < 4; ++r) dst[tb * 4 + r] = acc2[tb][r];
        }
        __syncthreads();
        if (w < 2) {
            const float* src = red + ((size_t)((w & 1) * 64 + l)) * 16;
            const int c = ml;   // D2 col = lane&15
            if (c < NC) {
                const float b2v = b2[e * NC + c];
#pragma unroll
                for (int tb = 0; tb < 4; ++tb) {
#pragma unroll
                    for (int r = 0; r < 4; ++r) {
                        float v = acc2[tb][r] + src[tb * 4 + r];
                        const int bg = b0 + wn + 16 * tb + 4 * q + r;
                        const float wgt = wg[(size_t)bg * NE + e];
                        atomicAdd(&logits[(size_t)bg * NC + c], wgt * (v + b2v));
                    }
                }
            }
        }
        // next pop's __syncthreads keeps red readers ahead of next ht writers
    }
}

// ---------------------------------------------------------------------------
extern "C" void kernel_launch(void* const* d_in, const int* in_sizes, int n_in,
                              void* d_out, int out_size, void* d_ws, size_t ws_size,
                              hipStream_t stream) {
    const float* feat  = (const float*)d_in[0];
    const float* z     = (const float*)d_in[1];
    const float* mu    = (const float*)d_in[2];
    const float* gamma = (const float*)d_in[3];
    const float* beta  = (const float*)d_in[4];
    const float* W1    = (const float*)d_in[5];
    const float* b1    = (const float*)d_in[6];
    const float* W2    = (const float*)d_in[7];
    const float* b2    = (const float*)d_in[8];
    const int*   tau   = (const int*)d_in[9];

    float* logits = (float*)d_out;                 // [B][NC]
    float* wout   = logits + (size_t)NB * NC;      // [B][NE]

    char* ws = (char*)d_ws;
    unsigned short* xhat = (unsigned short*)ws;                       // 33.5 MB
    unsigned short* w1t  = (unsigned short*)(ws + 33554432);          // 33.5 MB
    unsigned short* w2t  = (unsigned short*)(ws + 67108864);          // 0.5 MB
    float*          b1p  = (float*)(ws + 67633152);                   // 64 KB
    int*            qcnt = (int*)(ws + 67698688);                     // 4 B

    k_gate<<<NB / 4, 256, 0, stream>>>(z, mu, tau, wout, logits);
    k_ln<<<NB, 256, 0, stream>>>(feat, xhat);
    k_w2prep<<<(NE * 16 * HID) / 256, 256, 0, stream>>>(W2, b1, w2t, b1p, qcnt);
    k_w1prep<<<dim3(HID / 64, DIN / 64, NE), 256, 0, stream>>>(W1, gamma, beta, w1t, b1p);
    moe_main<<<dim3(GRID_MAIN), 256, 0, stream>>>(xhat, w1t, b1p, w2t, b2,
                                                  wout, logits, qcnt);
}

// Round 5
// 793.241 us; speedup vs baseline: 2.5624x; 1.1305x over previous
//
#include <hip/hip_runtime.h>
#include <hip/hip_bf16.h>
#include <cstdint>

// Problem constants
#define NB     16384   // batch
#define DIN    1024
#define HID    2048
#define NE     8
#define NC     8
#define DZ     256

// Main GEMM tiling
#define BM     128     // hidden rows per chunk
#define BNB    128     // batch cols per tile
#define BK     64      // R4: doubled (R3 latency-bound: 900cyc round/310cyc MFMA)
#define KSTEPS (DIN/BK)    // 16
#define NUNITS 2048        // 128 btiles x 8 experts x 2 hid-halves
#define GRID_MAIN 768      // 3 blocks/CU persistent

typedef short bf16x8 __attribute__((ext_vector_type(8)));
typedef float f32x4  __attribute__((ext_vector_type(4)));

__device__ __forceinline__ unsigned short f2bf(float f) {
    unsigned int u = __float_as_uint(f);
    unsigned int r = (u + 0x7FFFu + ((u >> 16) & 1u)) >> 16;
    return (unsigned short)r;
}

__device__ __forceinline__ void async_copy16(const void* g, void* l) {
    __builtin_amdgcn_global_load_lds(
        (const __attribute__((address_space(1))) unsigned int*)g,
        (__attribute__((address_space(3))) unsigned int*)l, 16, 0, 0);
}

// ---------------------------------------------------------------------------
// Gate: w = softmax(cos_sim(z, mu)/tau). One wave per row. Also zeroes logits.
// ---------------------------------------------------------------------------
__global__ __launch_bounds__(256) void k_gate(const float* __restrict__ z,
                                              const float* __restrict__ mu,
                                              const int* __restrict__ tau_i,
                                              float* __restrict__ wout,
                                              float* __restrict__ logits) {
    int row = blockIdx.x * 4 + (threadIdx.x >> 6);
    int l = threadIdx.x & 63;
    float4 zv = *(const float4*)&z[(size_t)row * DZ + l * 4];
    float zz = zv.x * zv.x + zv.y * zv.y + zv.z * zv.z + zv.w * zv.w;
    float dots[NE], mm[NE];
#pragma unroll
    for (int e = 0; e < NE; ++e) {
        float4 m = *(const float4*)&mu[e * DZ + l * 4];
        dots[e] = zv.x * m.x + zv.y * m.y + zv.z * m.z + zv.w * m.w;
        mm[e]   = m.x * m.x + m.y * m.y + m.z * m.z + m.w * m.w;
    }
#pragma unroll
    for (int off = 32; off; off >>= 1) {
        zz += __shfl_xor(zz, off);
#pragma unroll
        for (int e = 0; e < NE; ++e) {
            dots[e] += __shfl_xor(dots[e], off);
            mm[e]   += __shfl_xor(mm[e], off);
        }
    }
    float zn = fmaxf(sqrtf(zz), 1e-12f);
    float tau = fmaxf(1e-6f, (float)tau_i[0]);
    float s[NE], mx = -1e30f;
#pragma unroll
    for (int e = 0; e < NE; ++e) {
        s[e] = dots[e] / (zn * fmaxf(sqrtf(mm[e]), 1e-12f)) / tau;
        mx = fmaxf(mx, s[e]);
    }
    float sum = 0.f;
#pragma unroll
    for (int e = 0; e < NE; ++e) { s[e] = expf(s[e] - mx); sum += s[e]; }
    float inv = 1.f / sum;
    if (l < NE) {
        wout[(size_t)row * NE + l]   = s[l] * inv;
        logits[(size_t)row * NE + l] = 0.f;   // zero-init for atomics
    }
}

// ---------------------------------------------------------------------------
// LayerNorm (shared part) -> bf16 xhat. One block per row.
// ---------------------------------------------------------------------------
__global__ __launch_bounds__(256) void k_ln(const float* __restrict__ feat,
                                            unsigned short* __restrict__ xhat) {
    int row = blockIdx.x;
    int t = threadIdx.x;
    float4 v = *(const float4*)&feat[(size_t)row * DIN + t * 4];
    float s  = v.x + v.y + v.z + v.w;
    float sq = v.x * v.x + v.y * v.y + v.z * v.z + v.w * v.w;
#pragma unroll
    for (int off = 32; off; off >>= 1) {
        s  += __shfl_down(s, off);
        sq += __shfl_down(sq, off);
    }
    __shared__ float ls[8];
    int w = t >> 6, l = t & 63;
    if (l == 0) { ls[w] = s; ls[4 + w] = sq; }
    __syncthreads();
    s  = ls[0] + ls[1] + ls[2] + ls[3];
    sq = ls[4] + ls[5] + ls[6] + ls[7];
    float mean = s * (1.f / DIN);
    float var  = sq * (1.f / DIN) - mean * mean;
    float r = 1.0f / sqrtf(var + 1e-5f);
    uint2 p;
    p.x = (unsigned)f2bf((v.x - mean) * r) | ((unsigned)f2bf((v.y - mean) * r) << 16);
    p.y = (unsigned)f2bf((v.z - mean) * r) | ((unsigned)f2bf((v.w - mean) * r) << 16);
    *(uint2*)&xhat[(size_t)row * DIN + t * 4] = p;
}

// ---------------------------------------------------------------------------
// W2 transpose->bf16 (padded [E][16][HID]), b1p init, and work-queue zero.
// ---------------------------------------------------------------------------
__global__ __launch_bounds__(256) void k_w2prep(const float* __restrict__ W2,
                                                const float* __restrict__ b1,
                                                unsigned short* __restrict__ w2t,
                                                float* __restrict__ b1p,
                                                int* __restrict__ qcounter) {
    int i = blockIdx.x * 256 + threadIdx.x;   // 8*16*2048 = 262144
    if (i == 0) qcounter[0] = 0;              // ws is re-poisoned each launch
    int e = i >> 15;
    int rem = i & 32767;
    int c = rem >> 11;
    int h = rem & 2047;
    float v = (c < NC) ? W2[((size_t)(e * HID + h)) * NC + c] : 0.f;
    w2t[i] = f2bf(v);
    if (i < NE * HID) b1p[i] = b1[i];
}

// ---------------------------------------------------------------------------
// W1 fold+transpose: W1t[e][h][d] = bf16(gamma[e][d] * W1[e][d][h]);
// b1p[e][h] += sum_d beta[e][d]*W1[e][d][h].  64x64 LDS tile transpose.
// ---------------------------------------------------------------------------
__global__ __launch_bounds__(256) void k_w1prep(const float* __restrict__ W1,
                                                const float* __restrict__ gamma,
                                                const float* __restrict__ beta,
                                                unsigned short* __restrict__ w1t,
                                                float* __restrict__ b1p) {
    __shared__ float tile[64][65];   // [h-local][d-local], unscaled
    int e  = blockIdx.z;
    int d0 = blockIdx.y * 64;
    int h0 = blockIdx.x * 64;
    int tx = threadIdx.x & 15, ty = threadIdx.x >> 4;
#pragma unroll
    for (int rr = 0; rr < 4; ++rr) {
        int d = ty + rr * 16;
        float4 v = *(const float4*)&W1[((size_t)e * DIN + d0 + d) * HID + h0 + tx * 4];
        tile[tx * 4 + 0][d] = v.x;
        tile[tx * 4 + 1][d] = v.y;
        tile[tx * 4 + 2][d] = v.z;
        tile[tx * 4 + 3][d] = v.w;
    }
    __syncthreads();
    float4 g = *(const float4*)&gamma[(size_t)e * DIN + d0 + tx * 4];
#pragma unroll
    for (int rr = 0; rr < 4; ++rr) {
        int h = ty + rr * 16;
        uint2 p;
        p.x = (unsigned)f2bf(tile[h][tx * 4 + 0] * g.x) |
              ((unsigned)f2bf(tile[h][tx * 4 + 1] * g.y) << 16);
        p.y = (unsigned)f2bf(tile[h][tx * 4 + 2] * g.z) |
              ((unsigned)f2bf(tile[h][tx * 4 + 3] * g.w) << 16);
        *(uint2*)&w1t[((size_t)e * HID + h0 + h) * DIN + d0 + tx * 4] = p;
    }
    if (threadIdx.x < 64) {
        int h = threadIdx.x;
        float sacc = 0.f;
        for (int r = 0; r < 64; ++r)
            sacc += beta[(size_t)e * DIN + d0 + r] * tile[h][r];
        atomicAdd(&b1p[(size_t)e * HID + h0 + h], sacc);
    }
}

// ---------------------------------------------------------------------------
// Fused main kernel, R4: BK=64 K-loop (16 rounds/chunk instead of 32) at
// unchanged 3 blocks/CU. R3's model: ~900cyc round latency vs 310cyc MFMA
// content -> latency-serialized (MfmaUtil 33%). Doubling per-round compute
// (620cyc MFMA/SIMD, 3 blocks -> 1860cyc demand per round) tips the balance
// to pipe-bound. LDS = 16+16+20 = 52KB -> 3 blocks/CU still fit (m132's
// BK=128 failure was the occupancy loss, not the BK concept).
// Swizzle: 16B chunk c (0..7) of row r stored at c ^ (r&7); read side
// chunk (kk*4+q) ^ (ml&7) -> 2-way bank aliasing (free). K=32 sub-steps kept
// sequential (#pragma unroll 1) to cap live fragments (reg budget 170/wave).
// ---------------------------------------------------------------------------
__global__ __launch_bounds__(256, 3) void moe_main(
        const unsigned short* __restrict__ xhat,   // [B][DIN] bf16
        const unsigned short* __restrict__ w1t,    // [E][HID][DIN] bf16
        const float* __restrict__ b1p,             // [E][HID]
        const unsigned short* __restrict__ w2t,    // [E][16][HID] bf16 (c>=8 zero)
        const float* __restrict__ b2,              // [E][NC]
        const float* __restrict__ wg,              // [B][NE]
        float* __restrict__ logits,                // [B][NC]
        int* __restrict__ qcounter) {
    __shared__ __align__(16) short lds_a[BM * BK];      // 16 KB, swizzled
    __shared__ __align__(16) short lds_b[BNB * BK];     // 16 KB, swizzled
    __shared__ __align__(16) char  lds_ht[4 * 64 * 80]; // 20 KB per-wave hT
    __shared__ int s_u;

    const int t = threadIdx.x;
    const int w = t >> 6, l = t & 63;
    const int q = l >> 4, ml = l & 15;
    const int wm = (w >> 1) * 64;     // wave's hid-half within chunk
    const int wn = (w & 1) * 64;      // wave's b-half

    // Staging: per issue (it), 256 threads cover 32 rows x 8 chunks of 16B.
    // row = it*32 + w*8 + (l>>3); global k-chunk = (l&7) ^ (row&7) = (l&7)^((l>>3)&7).
    const int strow  = w * 8 + (l >> 3);                  // + it*32
    const int kslot8 = (((l & 7) ^ ((l >> 3) & 7))) * 8;  // elems
    const int rswz   = ml & 7;                            // read-side row xor
    char* myht = lds_ht + w * 5120;   // 64 rows(b) x 80 B

    for (;;) {
        if (t == 0) s_u = atomicAdd(qcounter, 1);
        __syncthreads();
        const int u = s_u;
        if (u >= NUNITS) break;
        const int btile = u & 127;
        const int e     = (u >> 7) & 7;
        const int half  = u >> 10;
        const int b0 = btile * BNB;
        const unsigned short* gA = w1t + (size_t)e * HID * DIN;
        const unsigned short* gB = xhat + (size_t)b0 * DIN;

        f32x4 acc2[4];
#pragma unroll
        for (int tb = 0; tb < 4; ++tb) acc2[tb] = (f32x4){0.f, 0.f, 0.f, 0.f};

        for (int ch = half * 8; ch < half * 8 + 8; ++ch) {
            const int hid0 = ch * BM;
            f32x4 acc[4][4];
#pragma unroll
            for (int i = 0; i < 4; ++i)
#pragma unroll
                for (int j = 0; j < 4; ++j) acc[i][j] = (f32x4){0.f, 0.f, 0.f, 0.f};

            for (int ks = 0; ks < KSTEPS; ++ks) {
                const int k0 = ks * BK;
#pragma unroll
                for (int it = 0; it < 4; ++it) {
                    const int row = it * 32 + strow;
                    async_copy16(gA + (size_t)(hid0 + row) * DIN + k0 + kslot8,
                                 (char*)lds_a + it * 4096 + w * 1024 + (l << 4));
                    async_copy16(gB + (size_t)row * DIN + k0 + kslot8,
                                 (char*)lds_b + it * 4096 + w * 1024 + (l << 4));
                }
                __syncthreads();   // drains vmcnt before barrier (m97 pattern)
#pragma unroll 1
                for (int kk = 0; kk < 2; ++kk) {   // sequential: cap live VGPRs
                    const int cswz = ((kk * 4 + q) ^ rswz) * 8;
                    bf16x8 aF[4], bF[4];
#pragma unroll
                    for (int i = 0; i < 4; ++i)
                        aF[i] = *(const bf16x8*)&lds_a[(wm + 16 * i + ml) * BK + cswz];
#pragma unroll
                    for (int j = 0; j < 4; ++j)
                        bF[j] = *(const bf16x8*)&lds_b[(wn + 16 * j + ml) * BK + cswz];
#pragma unroll
                    for (int i = 0; i < 4; ++i)
#pragma unroll
                        for (int j = 0; j < 4; ++j)
                            acc[i][j] = __builtin_amdgcn_mfma_f32_16x16x32_bf16(
                                aF[i], bF[j], acc[i][j], 0, 0, 0);
                }
                __syncthreads();   // all waves done reading before next stage
            }

            // ---- chunk epilogue, 2 passes of 32 hid each ----
#pragma unroll
            for (int s = 0; s < 2; ++s) {
#pragma unroll
                for (int i2 = 0; i2 < 2; ++i2) {
                    const int i = 2 * s + i2;
                    const float4 bias = *(const float4*)
                        &b1p[(size_t)e * HID + hid0 + wm + 16 * i + 4 * q];
#pragma unroll
                    for (int j = 0; j < 4; ++j) {
                        float v0 = fmaxf(acc[i][j].x + bias.x, 0.f);
                        float v1 = fmaxf(acc[i][j].y + bias.y, 0.f);
                        float v2 = fmaxf(acc[i][j].z + bias.z, 0.f);
                        float v3 = fmaxf(acc[i][j].w + bias.w, 0.f);
                        uint2 p;
                        p.x = (unsigned)f2bf(v0) | ((unsigned)f2bf(v1) << 16);
                        p.y = (unsigned)f2bf(v2) | ((unsigned)f2bf(v3) << 16);
                        const int brow = 16 * j + ml;   // local b (0..63)
                        *(uint2*)(myht + brow * 80 + (16 * i2 + 4 * q) * 2) = p;
                    }
                }
                // second GEMM over this 32-hid slab (wave-private ht)
                const bf16x8 b2f = *(const bf16x8*)&w2t[((size_t)e * 16 + ml) * HID +
                                                        hid0 + wm + 32 * s + 8 * q];
#pragma unroll
                for (int tb = 0; tb < 4; ++tb) {
                    const bf16x8 a2f =
                        *(const bf16x8*)(myht + (16 * tb + ml) * 80 + q * 16);
                    acc2[tb] = __builtin_amdgcn_mfma_f32_16x16x32_bf16(
                        a2f, b2f, acc2[tb], 0, 0, 0);
                }
            }
        }

        // ---- cross-wave (hid-half) reduction of acc2, gated atomic store ----
        __syncthreads();
        float* red = (float*)lds_ht;
        if (w >= 2) {
            float* dst = red + ((size_t)((w & 1) * 64 + l)) * 16;
#pragma unroll
            for (int tb = 0; tb < 4; ++tb)
#pragma unroll
                for (int r = 0; r < 4; ++r) dst[tb * 4 + r] = acc2[tb][r];
        }
        __syncthreads();
        if (w < 2) {
            const float* src = red + ((size_t)((w & 1) * 64 + l)) * 16;
            const int c = ml;   // D2 col = lane&15
            if (c < NC) {
                const float b2v = b2[e * NC + c];
#pragma unroll
                for (int tb = 0; tb < 4; ++tb) {
#pragma unroll
                    for (int r = 0; r < 4; ++r) {
                        float v = acc2[tb][r] + src[tb * 4 + r];
                        const int bg = b0 + wn + 16 * tb + 4 * q + r;
                        const float wgt = wg[(size_t)bg * NE + e];
                        atomicAdd(&logits[(size_t)bg * NC + c], wgt * (v + b2v));
                    }
                }
            }
        }
        // next pop's __syncthreads keeps red readers ahead of next ht writers
    }
}

// ---------------------------------------------------------------------------
extern "C" void kernel_launch(void* const* d_in, const int* in_sizes, int n_in,
                              void* d_out, int out_size, void* d_ws, size_t ws_size,
                              hipStream_t stream) {
    const float* feat  = (const float*)d_in[0];
    const float* z     = (const float*)d_in[1];
    const float* mu    = (const float*)d_in[2];
    const float* gamma = (const float*)d_in[3];
    const float* beta  = (const float*)d_in[4];
    const float* W1    = (const float*)d_in[5];
    const float* b1    = (const float*)d_in[6];
    const float* W2    = (const float*)d_in[7];
    const float* b2    = (const float*)d_in[8];
    const int*   tau   = (const int*)d_in[9];

    float* logits = (float*)d_out;                 // [B][NC]
    float* wout   = logits + (size_t)NB * NC;      // [B][NE]

    char* ws = (char*)d_ws;
    unsigned short* xhat = (unsigned short*)ws;                       // 33.5 MB
    unsigned short* w1t  = (unsigned short*)(ws + 33554432);          // 33.5 MB
    unsigned short* w2t  = (unsigned short*)(ws + 67108864);          // 0.5 MB
    float*          b1p  = (float*)(ws + 67633152);                   // 64 KB
    int*            qcnt = (int*)(ws + 67698688);                     // 4 B

    k_gate<<<NB / 4, 256, 0, stream>>>(z, mu, tau, wout, logits);
    k_ln<<<NB, 256, 0, stream>>>(feat, xhat);
    k_w2prep<<<(NE * 16 * HID) / 256, 256, 0, stream>>>(W2, b1, w2t, b1p, qcnt);
    k_w1prep<<<dim3(HID / 64, DIN / 64, NE), 256, 0, stream>>>(W1, gamma, beta, w1t, b1p);
    moe_main<<<dim3(GRID_MAIN), 256, 0, stream>>>(xhat, w1t, b1p, w2t, b2,
                                                  wout, logits, qcnt);
}

// Round 6
// 724.993 us; speedup vs baseline: 2.8036x; 1.0941x over previous
//
#include <hip/hip_runtime.h>
#include <hip/hip_bf16.h>
#include <cstdint>

// Problem constants
#define NB     16384   // batch
#define DIN    1024
#define HID    2048
#define NE     8
#define NC     8
#define DZ     256

// Main GEMM tiling (R5: 256x128 block, 128x64 wave tile, BK=64)
#define BM     256     // hidden rows per chunk (block tile M)
#define BNB    128     // batch cols per tile
#define BK     64
#define KSTEPS (DIN/BK)    // 16
#define NUNITS 2048        // 128 btiles x 8 experts x 2 hid-halves (4 chunks each)
#define GRID_MAIN 512      // 2 blocks/CU persistent

typedef short bf16x8 __attribute__((ext_vector_type(8)));
typedef float f32x4  __attribute__((ext_vector_type(4)));

__device__ __forceinline__ unsigned short f2bf(float f) {
    unsigned int u = __float_as_uint(f);
    unsigned int r = (u + 0x7FFFu + ((u >> 16) & 1u)) >> 16;
    return (unsigned short)r;
}

__device__ __forceinline__ void async_copy16(const void* g, void* l) {
    __builtin_amdgcn_global_load_lds(
        (const __attribute__((address_space(1))) unsigned int*)g,
        (__attribute__((address_space(3))) unsigned int*)l, 16, 0, 0);
}

// ---------------------------------------------------------------------------
// Gate: w = softmax(cos_sim(z, mu)/tau). One wave per row. Also initializes
// logits[b,c] = sum_e w[b,e]*b2[e,c]  (b2 folded here: the main kernel's
// hid-half units would otherwise double-add it -- R3/R4 latent bug).
// ---------------------------------------------------------------------------
__global__ __launch_bounds__(256) void k_gate(const float* __restrict__ z,
                                              const float* __restrict__ mu,
                                              const int* __restrict__ tau_i,
                                              const float* __restrict__ b2,
                                              float* __restrict__ wout,
                                              float* __restrict__ logits) {
    int row = blockIdx.x * 4 + (threadIdx.x >> 6);
    int l = threadIdx.x & 63;
    float4 zv = *(const float4*)&z[(size_t)row * DZ + l * 4];
    float zz = zv.x * zv.x + zv.y * zv.y + zv.z * zv.z + zv.w * zv.w;
    float dots[NE], mm[NE];
#pragma unroll
    for (int e = 0; e < NE; ++e) {
        float4 m = *(const float4*)&mu[e * DZ + l * 4];
        dots[e] = zv.x * m.x + zv.y * m.y + zv.z * m.z + zv.w * m.w;
        mm[e]   = m.x * m.x + m.y * m.y + m.z * m.z + m.w * m.w;
    }
#pragma unroll
    for (int off = 32; off; off >>= 1) {
        zz += __shfl_xor(zz, off);
#pragma unroll
        for (int e = 0; e < NE; ++e) {
            dots[e] += __shfl_xor(dots[e], off);
            mm[e]   += __shfl_xor(mm[e], off);
        }
    }
    float zn = fmaxf(sqrtf(zz), 1e-12f);
    float tau = fmaxf(1e-6f, (float)tau_i[0]);
    float s[NE], mx = -1e30f;
#pragma unroll
    for (int e = 0; e < NE; ++e) {
        s[e] = dots[e] / (zn * fmaxf(sqrtf(mm[e]), 1e-12f)) / tau;
        mx = fmaxf(mx, s[e]);
    }
    float sum = 0.f;
#pragma unroll
    for (int e = 0; e < NE; ++e) { s[e] = expf(s[e] - mx); sum += s[e]; }
    float inv = 1.f / sum;
    if (l < NE) {
        wout[(size_t)row * NE + l] = s[l] * inv;
        // logits init = sum_e w[e] * b2[e][c], c = l
        float acc = 0.f;
#pragma unroll
        for (int e = 0; e < NE; ++e) acc += s[e] * inv * b2[e * NC + l];
        logits[(size_t)row * NC + l] = acc;
    }
}

// ---------------------------------------------------------------------------
// LayerNorm (shared part) -> bf16 xhat. One block per row.
// ---------------------------------------------------------------------------
__global__ __launch_bounds__(256) void k_ln(const float* __restrict__ feat,
                                            unsigned short* __restrict__ xhat) {
    int row = blockIdx.x;
    int t = threadIdx.x;
    float4 v = *(const float4*)&feat[(size_t)row * DIN + t * 4];
    float s  = v.x + v.y + v.z + v.w;
    float sq = v.x * v.x + v.y * v.y + v.z * v.z + v.w * v.w;
#pragma unroll
    for (int off = 32; off; off >>= 1) {
        s  += __shfl_down(s, off);
        sq += __shfl_down(sq, off);
    }
    __shared__ float ls[8];
    int w = t >> 6, l = t & 63;
    if (l == 0) { ls[w] = s; ls[4 + w] = sq; }
    __syncthreads();
    s  = ls[0] + ls[1] + ls[2] + ls[3];
    sq = ls[4] + ls[5] + ls[6] + ls[7];
    float mean = s * (1.f / DIN);
    float var  = sq * (1.f / DIN) - mean * mean;
    float r = 1.0f / sqrtf(var + 1e-5f);
    uint2 p;
    p.x = (unsigned)f2bf((v.x - mean) * r) | ((unsigned)f2bf((v.y - mean) * r) << 16);
    p.y = (unsigned)f2bf((v.z - mean) * r) | ((unsigned)f2bf((v.w - mean) * r) << 16);
    *(uint2*)&xhat[(size_t)row * DIN + t * 4] = p;
}

// ---------------------------------------------------------------------------
// W2 transpose->bf16 (padded [E][16][HID]), b1p init, and work-queue zero.
// ---------------------------------------------------------------------------
__global__ __launch_bounds__(256) void k_w2prep(const float* __restrict__ W2,
                                                const float* __restrict__ b1,
                                                unsigned short* __restrict__ w2t,
                                                float* __restrict__ b1p,
                                                int* __restrict__ qcounter) {
    int i = blockIdx.x * 256 + threadIdx.x;   // 8*16*2048 = 262144
    if (i == 0) qcounter[0] = 0;              // ws is re-poisoned each launch
    int e = i >> 15;
    int rem = i & 32767;
    int c = rem >> 11;
    int h = rem & 2047;
    float v = (c < NC) ? W2[((size_t)(e * HID + h)) * NC + c] : 0.f;
    w2t[i] = f2bf(v);
    if (i < NE * HID) b1p[i] = b1[i];
}

// ---------------------------------------------------------------------------
// W1 fold+transpose: W1t[e][h][d] = bf16(gamma[e][d] * W1[e][d][h]);
// b1p[e][h] += sum_d beta[e][d]*W1[e][d][h].  64x64 LDS tile transpose.
// ---------------------------------------------------------------------------
__global__ __launch_bounds__(256) void k_w1prep(const float* __restrict__ W1,
                                                const float* __restrict__ gamma,
                                                const float* __restrict__ beta,
                                                unsigned short* __restrict__ w1t,
                                                float* __restrict__ b1p) {
    __shared__ float tile[64][65];   // [h-local][d-local], unscaled
    int e  = blockIdx.z;
    int d0 = blockIdx.y * 64;
    int h0 = blockIdx.x * 64;
    int tx = threadIdx.x & 15, ty = threadIdx.x >> 4;
#pragma unroll
    for (int rr = 0; rr < 4; ++rr) {
        int d = ty + rr * 16;
        float4 v = *(const float4*)&W1[((size_t)e * DIN + d0 + d) * HID + h0 + tx * 4];
        tile[tx * 4 + 0][d] = v.x;
        tile[tx * 4 + 1][d] = v.y;
        tile[tx * 4 + 2][d] = v.z;
        tile[tx * 4 + 3][d] = v.w;
    }
    __syncthreads();
    float4 g = *(const float4*)&gamma[(size_t)e * DIN + d0 + tx * 4];
#pragma unroll
    for (int rr = 0; rr < 4; ++rr) {
        int h = ty + rr * 16;
        uint2 p;
        p.x = (unsigned)f2bf(tile[h][tx * 4 + 0] * g.x) |
              ((unsigned)f2bf(tile[h][tx * 4 + 1] * g.y) << 16);
        p.y = (unsigned)f2bf(tile[h][tx * 4 + 2] * g.z) |
              ((unsigned)f2bf(tile[h][tx * 4 + 3] * g.w) << 16);
        *(uint2*)&w1t[((size_t)e * HID + h0 + h) * DIN + d0 + tx * 4] = p;
    }
    if (threadIdx.x < 64) {
        int h = threadIdx.x;
        float sacc = 0.f;
        for (int r = 0; r < 64; ++r)
            sacc += beta[(size_t)e * DIN + d0 + r] * tile[h][r];
        atomicAdd(&b1p[(size_t)e * HID + h0 + h], sacc);
    }
}

// ---------------------------------------------------------------------------
// Fused main kernel, R5: 256x128 block tile, 128x64 wave tile (acc[8][4],
// 128 AGPR), BK=64, 2 blocks/CU. R4 was LDS-BW-bound (96 KB/block-round =
// ~78% of the 85 B/cyc measured LDS ceiling, MfmaUtil 42%). Bigger wave
// tile cuts frag-read bytes/FLOP 25% (34.4 vs 45.7 B/kFLOP). Per-round
// MFMA content 1241 SIMD-cyc/block >> ~900cyc round latency, so 2-block
// overlap suffices. b2 is handled in k_gate (R3/R4 double-add bug fixed).
// ---------------------------------------------------------------------------
__global__ __launch_bounds__(256, 2) void moe_main(
        const unsigned short* __restrict__ xhat,   // [B][DIN] bf16
        const unsigned short* __restrict__ w1t,    // [E][HID][DIN] bf16
        const float* __restrict__ b1p,             // [E][HID]
        const unsigned short* __restrict__ w2t,    // [E][16][HID] bf16 (c>=8 zero)
        const float* __restrict__ wg,              // [B][NE]
        float* __restrict__ logits,                // [B][NC]
        int* __restrict__ qcounter) {
    __shared__ __align__(16) short lds_a[BM * BK];      // 32 KB, swizzled
    __shared__ __align__(16) short lds_b[BNB * BK];     // 16 KB, swizzled
    __shared__ __align__(16) char  lds_ht[4 * 64 * 80]; // 20 KB per-wave hT
    __shared__ int s_u;

    const int t = threadIdx.x;
    const int w = t >> 6, l = t & 63;
    const int q = l >> 4, ml = l & 15;
    const int wm = (w >> 1) * 128;    // wave's hid-half within 256 chunk
    const int wn = (w & 1) * 64;      // wave's b-half

    // Staging: per issue, 256 threads cover 32 rows x 8 chunks of 16B.
    // row = it*32 + w*8 + (l>>3); phys k-chunk = (l&7), logical = (l&7)^(row&7).
    const int strow  = w * 8 + (l >> 3);
    const int kslot8 = (((l & 7) ^ ((l >> 3) & 7))) * 8;  // elems
    const int rswz   = ml & 7;                            // read-side row xor
    char* myht = lds_ht + w * 5120;   // 64 rows(b) x 80 B

    for (;;) {
        if (t == 0) s_u = atomicAdd(qcounter, 1);
        __syncthreads();
        const int u = s_u;
        if (u >= NUNITS) break;
        const int btile = u & 127;
        const int e     = (u >> 7) & 7;
        const int half  = u >> 10;
        const int b0 = btile * BNB;
        const unsigned short* gA = w1t + (size_t)e * HID * DIN;
        const unsigned short* gB = xhat + (size_t)b0 * DIN;

        f32x4 acc2[4];
#pragma unroll
        for (int tb = 0; tb < 4; ++tb) acc2[tb] = (f32x4){0.f, 0.f, 0.f, 0.f};

        for (int ch = half * 4; ch < half * 4 + 4; ++ch) {
            const int hid0 = ch * BM;
            f32x4 acc[8][4];
#pragma unroll
            for (int i = 0; i < 8; ++i)
#pragma unroll
                for (int j = 0; j < 4; ++j) acc[i][j] = (f32x4){0.f, 0.f, 0.f, 0.f};

            for (int ks = 0; ks < KSTEPS; ++ks) {
                const int k0 = ks * BK;
#pragma unroll
                for (int it = 0; it < 8; ++it) {
                    const int row = it * 32 + strow;
                    async_copy16(gA + (size_t)(hid0 + row) * DIN + k0 + kslot8,
                                 (char*)lds_a + it * 4096 + w * 1024 + (l << 4));
                    if (it < 4)
                        async_copy16(gB + (size_t)row * DIN + k0 + kslot8,
                                     (char*)lds_b + it * 4096 + w * 1024 + (l << 4));
                }
                __syncthreads();   // drains vmcnt before barrier (m97 pattern)
#pragma unroll 1
                for (int kk = 0; kk < 2; ++kk) {   // sequential: cap live VGPRs
                    const int cswz = ((kk * 4 + q) ^ rswz) * 8;
                    bf16x8 bF[4];
#pragma unroll
                    for (int j = 0; j < 4; ++j)
                        bF[j] = *(const bf16x8*)&lds_b[(wn + 16 * j + ml) * BK + cswz];
#pragma unroll
                    for (int i = 0; i < 8; ++i) {
                        const bf16x8 aF =
                            *(const bf16x8*)&lds_a[(wm + 16 * i + ml) * BK + cswz];
#pragma unroll
                        for (int j = 0; j < 4; ++j)
                            acc[i][j] = __builtin_amdgcn_mfma_f32_16x16x32_bf16(
                                aF, bF[j], acc[i][j], 0, 0, 0);
                    }
                }
                __syncthreads();   // all waves done reading before next stage
            }

            // ---- chunk epilogue, 4 slabs of 32 hid each ----
#pragma unroll
            for (int s = 0; s < 4; ++s) {
#pragma unroll
                for (int i2 = 0; i2 < 2; ++i2) {
                    const int i = 2 * s + i2;
                    const float4 bias = *(const float4*)
                        &b1p[(size_t)e * HID + hid0 + wm + 16 * i + 4 * q];
#pragma unroll
                    for (int j = 0; j < 4; ++j) {
                        float v0 = fmaxf(acc[i][j].x + bias.x, 0.f);
                        float v1 = fmaxf(acc[i][j].y + bias.y, 0.f);
                        float v2 = fmaxf(acc[i][j].z + bias.z, 0.f);
                        float v3 = fmaxf(acc[i][j].w + bias.w, 0.f);
                        uint2 p;
                        p.x = (unsigned)f2bf(v0) | ((unsigned)f2bf(v1) << 16);
                        p.y = (unsigned)f2bf(v2) | ((unsigned)f2bf(v3) << 16);
                        const int brow = 16 * j + ml;   // local b (0..63)
                        *(uint2*)(myht + brow * 80 + (16 * i2 + 4 * q) * 2) = p;
                    }
                }
                // second GEMM over this 32-hid slab (wave-private ht)
                const bf16x8 b2f = *(const bf16x8*)&w2t[((size_t)e * 16 + ml) * HID +
                                                        hid0 + wm + 32 * s + 8 * q];
#pragma unroll
                for (int tb = 0; tb < 4; ++tb) {
                    const bf16x8 a2f =
                        *(const bf16x8*)(myht + (16 * tb + ml) * 80 + q * 16);
                    acc2[tb] = __builtin_amdgcn_mfma_f32_16x16x32_bf16(
                        a2f, b2f, acc2[tb], 0, 0, 0);
                }
            }
        }

        // ---- cross-wave (hid-half) reduction of acc2, gated atomic store ----
        __syncthreads();
        float* red = (float*)lds_ht;
        if (w >= 2) {
            float* dst = red + ((size_t)((w & 1) * 64 + l)) * 16;
#pragma unroll
            for (int tb = 0; tb < 4; ++tb)
#pragma unroll
                for (int r = 0; r < 4; ++r) dst[tb * 4 + r] = acc2[tb][r];
        }
        __syncthreads();
        if (w < 2) {
            const float* src = red + ((size_t)((w & 1) * 64 + l)) * 16;
            const int c = ml;   // D2 col = lane&15
            if (c < NC) {
#pragma unroll
                for (int tb = 0; tb < 4; ++tb) {
#pragma unroll
                    for (int r = 0; r < 4; ++r) {
                        float v = acc2[tb][r] + src[tb * 4 + r];
                        const int bg = b0 + wn + 16 * tb + 4 * q + r;
                        const float wgt = wg[(size_t)bg * NE + e];
                        atomicAdd(&logits[(size_t)bg * NC + c], wgt * v);
                    }
                }
            }
        }
        // next pop's __syncthreads keeps red readers ahead of next ht writers
    }
}

// ---------------------------------------------------------------------------
extern "C" void kernel_launch(void* const* d_in, const int* in_sizes, int n_in,
                              void* d_out, int out_size, void* d_ws, size_t ws_size,
                              hipStream_t stream) {
    const float* feat  = (const float*)d_in[0];
    const float* z     = (const float*)d_in[1];
    const float* mu    = (const float*)d_in[2];
    const float* gamma = (const float*)d_in[3];
    const float* beta  = (const float*)d_in[4];
    const float* W1    = (const float*)d_in[5];
    const float* b1    = (const float*)d_in[6];
    const float* W2    = (const float*)d_in[7];
    const float* b2    = (const float*)d_in[8];
    const int*   tau   = (const int*)d_in[9];

    float* logits = (float*)d_out;                 // [B][NC]
    float* wout   = logits + (size_t)NB * NC;      // [B][NE]

    char* ws = (char*)d_ws;
    unsigned short* xhat = (unsigned short*)ws;                       // 33.5 MB
    unsigned short* w1t  = (unsigned short*)(ws + 33554432);          // 33.5 MB
    unsigned short* w2t  = (unsigned short*)(ws + 67108864);          // 0.5 MB
    float*          b1p  = (float*)(ws + 67633152);                   // 64 KB
    int*            qcnt = (int*)(ws + 67698688);                     // 4 B

    k_gate<<<NB / 4, 256, 0, stream>>>(z, mu, tau, b2, wout, logits);
    k_ln<<<NB, 256, 0, stream>>>(feat, xhat);
    k_w2prep<<<(NE * 16 * HID) / 256, 256, 0, stream>>>(W2, b1, w2t, b1p, qcnt);
    k_w1prep<<<dim3(HID / 64, DIN / 64, NE), 256, 0, stream>>>(W1, gamma, beta, w1t, b1p);
    moe_main<<<dim3(GRID_MAIN), 256, 0, stream>>>(xhat, w1t, b1p, w2t,
                                                  wout, logits, qcnt);
}